// Round 12
// baseline (990.344 us; speedup 1.0000x reference)
//
#include <hip/hip_runtime.h>
#include <math.h>

#define T_STEPS 128
#define B_SZ 128
#define D_SZ 1024
#define H_SZ 1024
#define G4 4096
#define KW 2048  // rows of W = D+H
#define DIAG_STEPS 32

typedef __attribute__((ext_vector_type(8))) short bf16x8;
typedef __attribute__((ext_vector_type(4))) float f32x4;
typedef unsigned short ushort_t;
typedef unsigned int uint_t;
typedef unsigned long long ull_t;

__device__ __forceinline__ float sigf(float x) { return 1.0f / (1.0f + __expf(-x)); }
__device__ __forceinline__ float tanhfast(float x) { return 1.0f - 2.0f * sigf(-2.0f * x); }

__device__ __forceinline__ ushort_t f2bf(float f) {
  uint_t u = __float_as_uint(f);
  return (ushort_t)((u + 0x7fffu + ((u >> 16) & 1u)) >> 16);
}
__device__ __forceinline__ float bf2f(ushort_t s) {
  return __uint_as_float(((uint_t)s) << 16);
}

#define GLOAD_LDS16(gp, lp)                                                  \
  __builtin_amdgcn_global_load_lds(                                          \
      (const __attribute__((address_space(1))) unsigned int*)(const void*)(gp), \
      (__attribute__((address_space(3))) unsigned int*)(void*)(lp), 16, 0, 0)

// ---------------------------------------------------------------------------
// x fp32 [16384][1024] -> bf16 same layout. 8 elems/thread.
// ---------------------------------------------------------------------------
__global__ __launch_bounds__(256) void convert_x(const float* __restrict__ x,
                                                 ushort_t* __restrict__ xbf) {
  const size_t i8 = ((size_t)blockIdx.x * 256 + threadIdx.x) * 8;
  if (i8 + 8 > (size_t)T_STEPS * B_SZ * D_SZ) return;
  float4 a = *(const float4*)&x[i8];
  float4 b = *(const float4*)&x[i8 + 4];
  ushort_t o[8] = {f2bf(a.x), f2bf(a.y), f2bf(a.z), f2bf(a.w),
                   f2bf(b.x), f2bf(b.y), f2bf(b.z), f2bf(b.w)};
  *(uint4*)&xbf[i8] = *(uint4*)o;
}

// ---------------------------------------------------------------------------
// W fp32 [2048][4096] -> WT bf16 [4096][2048]  (WT[n][k] = W[k][n])
// ---------------------------------------------------------------------------
__global__ __launch_bounds__(256) void transpose_w(const float* __restrict__ W,
                                                   ushort_t* __restrict__ WT) {
  __shared__ float t[32][33];
  const int tx = threadIdx.x & 31;
  const int ty = threadIdx.x >> 5;  // 0..7
  const int k0 = blockIdx.x * 32;
  const int n0 = blockIdx.y * 32;
#pragma unroll
  for (int i = 0; i < 4; ++i)
    t[ty + i * 8][tx] = W[(size_t)(k0 + ty + i * 8) * G4 + n0 + tx];
  __syncthreads();
#pragma unroll
  for (int i = 0; i < 4; ++i)
    WT[(size_t)(n0 + ty + i * 8) * KW + k0 + tx] = f2bf(t[tx][ty + i * 8]);
}

// ---------------------------------------------------------------------------
// hbf0 = bf16(h0 * (1-reset[0]))
// ---------------------------------------------------------------------------
__global__ __launch_bounds__(256) void init_state(const float* __restrict__ h0,
                                                  const float* __restrict__ reset0,
                                                  ushort_t* __restrict__ hbf0) {
  const int i = blockIdx.x * 256 + threadIdx.x;
  if (i >= B_SZ * H_SZ) return;
  hbf0[i] = f2bf(h0[i] * (1.0f - reset0[i >> 10]));
}

// ---------------------------------------------------------------------------
// Gate pre-activation from x (v3 layout, supertile-swizzled). Unchanged R11.
// ---------------------------------------------------------------------------
__global__ __launch_bounds__(256) void xw_mfma3(const ushort_t* __restrict__ xbf,
                                                const ushort_t* __restrict__ WT,
                                                const float* __restrict__ bias,
                                                ushort_t* __restrict__ xwg) {
  __shared__ ushort_t Asb[2][128 * 64];
  __shared__ ushort_t Bsb[2][128 * 64];

  const int bid = blockIdx.x;
  const int xcd = bid & 7;
  const int ib = bid >> 3;
  const int mt = (ib >> 5) * 8 + (ib & 7);
  const int nt = xcd * 4 + ((ib >> 3) & 3);
  const int m0 = mt * 128, n0 = nt * 128;
  const int tid = threadIdx.x, lane = tid & 63, wid = tid >> 6;
  const int wr = wid >> 1, wc = wid & 1;
  const int lr = lane & 15, ko = lane >> 4;
  const int srow = lane >> 3;
  const int skb = (lane & 7) * 16;

  f32x4 acc[4][4] = {};

#define XW_STAGE(buf, kt)                                                      \
  {                                                                            \
    const int k0b = (kt) * 128;                                                \
    _Pragma("unroll") for (int i = 0; i < 4; ++i) {                            \
      const int c = wid * 4 + i;                                               \
      const int row = c * 8 + srow;                                            \
      const int sw = skb ^ ((row & 7) << 4);                                   \
      GLOAD_LDS16((const char*)xbf + (size_t)(m0 + row) * 2048 + k0b + sw,     \
                  (char*)&Asb[buf][0] + c * 1024);                             \
      GLOAD_LDS16((const char*)WT + (size_t)(n0 + row) * 4096 + k0b + sw,      \
                  (char*)&Bsb[buf][0] + c * 1024);                             \
    }                                                                          \
  }

  XW_STAGE(0, 0);
  __syncthreads();
  const int xsw = (lr & 7) << 4;
  for (int kt = 0; kt < 16; ++kt) {
    if (kt + 1 < 16) XW_STAGE((kt + 1) & 1, kt + 1);
    const char* Ab = (const char*)&Asb[kt & 1][0] + (wr * 64 + lr) * 128;
    const char* Bb = (const char*)&Bsb[kt & 1][0] + (wc * 64 + lr) * 128;
#pragma unroll
    for (int ks = 0; ks < 2; ++ks) {
      const int kb = (ks * 64 + ko * 16) ^ xsw;
      bf16x8 a[4], b[4];
#pragma unroll
      for (int mi = 0; mi < 4; ++mi) a[mi] = *(const bf16x8*)(Ab + mi * 2048 + kb);
#pragma unroll
      for (int ni = 0; ni < 4; ++ni) b[ni] = *(const bf16x8*)(Bb + ni * 2048 + kb);
#pragma unroll
      for (int mi = 0; mi < 4; ++mi)
#pragma unroll
        for (int ni = 0; ni < 4; ++ni)
          acc[mi][ni] = __builtin_amdgcn_mfma_f32_16x16x32_bf16(a[mi], b[ni], acc[mi][ni], 0, 0, 0);
    }
    __syncthreads();
  }

  const int rr = ko * 4;
#pragma unroll
  for (int ni = 0; ni < 4; ++ni) {
    const int n = n0 + wc * 64 + ni * 16 + lr;
    const int g = n >> 10;
    const int jtn = (n & 1023) >> 4;
    const float bn = bias[n];
#pragma unroll
    for (int mi = 0; mi < 4; ++mi) {
      const int m = m0 + wr * 64 + mi * 16 + rr;
      const int tt = m >> 7;
      const int btp = (m & 127) >> 5;
      const int r32 = m & 31;
      ushort_t tmp[4];
#pragma unroll
      for (int r = 0; r < 4; ++r) tmp[r] = f2bf(acc[mi][ni][r] + bn);
      *(ull_t*)(xwg + (((size_t)tt * 4 + btp) * 64 + jtn) * 2048 + g * 512 + lr * 32 + r32) =
          *(ull_t*)tmp;
    }
  }
}

// ---------------------------------------------------------------------------
// Persistent LSTM recurrence v7. vs v6: (a) wave0-only poll + syncthreads
// broadcast (8x less poll traffic); (b) tail reorder: h-store + vmcnt drain +
// arrive FIRST, then out-store + next-step prefetch (drain covers only the
// 128 h sc-stores).
// ---------------------------------------------------------------------------
__global__ __launch_bounds__(512) void lstm_persist7(
    const ushort_t* __restrict__ hbf0,
    const float* __restrict__ c0,
    const float* __restrict__ reset,
    const ushort_t* __restrict__ xwg,
    const ushort_t* __restrict__ WT,
    float* __restrict__ out,
    ushort_t* __restrict__ hring,
    uint_t* __restrict__ bar) {
  __shared__ ushort_t WhL[64 * 512];
  __shared__ ushort_t Ah[32 * 1024];
  __shared__ float sc[2][4][16][17];

  const int tid = threadIdx.x;
  const int bid = blockIdx.x;
  const int jt = bid & 63;
  const int btp = bid >> 6;
  const int b0 = btp * 32;
  const int lane = tid & 63;
  const int wid = tid >> 6;
  const int g = wid & 3;
  const int mh = wid >> 2;
  const int lr = lane & 15;
  const int ko = lane >> 4;
  const size_t SE = (size_t)B_SZ * H_SZ;

  uint_t* const arr = bar + btp * 256;

  for (int p = 0; p < 8; ++p) {
    const int id = p * 512 + tid;
    const int wrw = id >> 6;
    const int kb = (id & 63) * 16;
    const int n = (wrw >> 4) * H_SZ + jt * 16 + (wrw & 15);
    const uint4 v = *(const uint4*)((const char*)WT + (size_t)n * 4096 + 2048 + kb);
    *(uint4*)((char*)WhL + wrw * 1024 + (kb ^ ((wrw & 7) << 4))) = v;
  }

  const char* wrow = (const char*)WT + (size_t)(g * H_SZ + jt * 16 + lr) * 4096;
  bf16x8 breg[16];
#pragma unroll
  for (int q = 0; q < 16; ++q)
    breg[q] = *(const bf16x8*)(wrow + 3072 + q * 64 + ko * 16);

  const int row = tid >> 4;
  const int col = tid & 15;
  const int b = b0 + row;
  const int j = jt * 16 + col;
  const size_t so = (size_t)b * H_SZ + j;
  float creg = c0[so] * (1.0f - reset[b]);

  const int swzl = (lr & 7) << 4;
  const char* aBase = (const char*)Ah + (mh * 16 + lr) * 2048;
  const char* bBase = (const char*)WhL + (g * 16 + lr) * 1024;

  ushort_t xq0, xq1, xq2, xq3;
  {
    const ushort_t* xp = xwg + (((size_t)btp) * 64 + jt) * 2048 + col * 32 + row;
    xq0 = xp[0]; xq1 = xp[512]; xq2 = xp[1024]; xq3 = xp[1536];
  }
  float mn = 1.0f - reset[B_SZ + b];

  for (int t = 0; t < T_STEPS; ++t) {
    if (t > 0) {
      if (wid == 0) {
        uint_t it = 0;
        for (;;) {
          const uint_t v = __hip_atomic_load(&arr[lane], __ATOMIC_RELAXED,
                                             __HIP_MEMORY_SCOPE_AGENT);
          if (__all((int)v >= t)) break;
          __builtin_amdgcn_s_sleep(1);
          if (++it > 1000000u) break;
        }
      }
      __syncthreads();
    }
    const char* hsrc = (t == 0) ? (const char*)hbf0
                                : (const char*)(hring + (size_t)t * SE);
#pragma unroll
    for (int i = 0; i < 8; ++i) {
      const int c = wid * 8 + i;
      const int hrow = c >> 1;
      const int half = (c & 1) * 1024;
      const int kb = half + lane * 16;
      const int src = kb ^ ((hrow & 7) << 4);
      GLOAD_LDS16(hsrc + (size_t)(b0 + hrow) * 2048 + src,
                  (char*)Ah + hrow * 2048 + half);
    }
    __syncthreads();

    f32x4 ac0 = {}, ac1 = {}, ac2 = {}, ac3 = {};
#pragma unroll
    for (int q = 0; q < 4; ++q) {
      bf16x8 a0 = *(const bf16x8*)(aBase + (((q * 4 + 0) * 64 + ko * 16) ^ swzl));
      bf16x8 b0f = *(const bf16x8*)(bBase + (((q * 4 + 0) * 64 + ko * 16) ^ swzl));
      ac0 = __builtin_amdgcn_mfma_f32_16x16x32_bf16(a0, b0f, ac0, 0, 0, 0);
      bf16x8 a1 = *(const bf16x8*)(aBase + (((q * 4 + 1) * 64 + ko * 16) ^ swzl));
      bf16x8 b1f = *(const bf16x8*)(bBase + (((q * 4 + 1) * 64 + ko * 16) ^ swzl));
      ac1 = __builtin_amdgcn_mfma_f32_16x16x32_bf16(a1, b1f, ac1, 0, 0, 0);
      bf16x8 a2 = *(const bf16x8*)(aBase + (((q * 4 + 2) * 64 + ko * 16) ^ swzl));
      bf16x8 b2f = *(const bf16x8*)(bBase + (((q * 4 + 2) * 64 + ko * 16) ^ swzl));
      ac2 = __builtin_amdgcn_mfma_f32_16x16x32_bf16(a2, b2f, ac2, 0, 0, 0);
      bf16x8 a3 = *(const bf16x8*)(aBase + (((q * 4 + 3) * 64 + ko * 16) ^ swzl));
      bf16x8 b3f = *(const bf16x8*)(bBase + (((q * 4 + 3) * 64 + ko * 16) ^ swzl));
      ac3 = __builtin_amdgcn_mfma_f32_16x16x32_bf16(a3, b3f, ac3, 0, 0, 0);
    }
#pragma unroll
    for (int q = 0; q < 4; ++q) {
      bf16x8 a0 = *(const bf16x8*)(aBase + (((16 + q * 4 + 0) * 64 + ko * 16) ^ swzl));
      ac0 = __builtin_amdgcn_mfma_f32_16x16x32_bf16(a0, breg[q * 4 + 0], ac0, 0, 0, 0);
      bf16x8 a1 = *(const bf16x8*)(aBase + (((16 + q * 4 + 1) * 64 + ko * 16) ^ swzl));
      ac1 = __builtin_amdgcn_mfma_f32_16x16x32_bf16(a1, breg[q * 4 + 1], ac1, 0, 0, 0);
      bf16x8 a2 = *(const bf16x8*)(aBase + (((16 + q * 4 + 2) * 64 + ko * 16) ^ swzl));
      ac2 = __builtin_amdgcn_mfma_f32_16x16x32_bf16(a2, breg[q * 4 + 2], ac2, 0, 0, 0);
      bf16x8 a3 = *(const bf16x8*)(aBase + (((16 + q * 4 + 3) * 64 + ko * 16) ^ swzl));
      ac3 = __builtin_amdgcn_mfma_f32_16x16x32_bf16(a3, breg[q * 4 + 3], ac3, 0, 0, 0);
    }
    const f32x4 acc = (ac0 + ac1) + (ac2 + ac3);
#pragma unroll
    for (int r = 0; r < 4; ++r) sc[mh][g][ko * 4 + r][lr] = acc[r];
    __syncthreads();

    const float gi = sc[row >> 4][0][row & 15][col] + bf2f(xq0);
    const float gg = sc[row >> 4][1][row & 15][col] + bf2f(xq1);
    const float gf = sc[row >> 4][2][row & 15][col] + bf2f(xq2);
    const float go = sc[row >> 4][3][row & 15][col] + bf2f(xq3);
    const float f = sigf(gf + 1.0f);
    const float cn = f * creg + sigf(gi) * tanhfast(gg);
    const float hn = sigf(go) * tanhfast(cn);
    creg = cn * mn;

    if (t < T_STEPS - 1) {
      // h-store + drain + arrive FIRST (critical path), out/prefetch after
      const uint_t hm = (uint_t)f2bf(hn * mn);
      const uint_t h1 = (uint_t)__shfl_down((int)hm, 1);
      const uint_t h2 = (uint_t)__shfl_down((int)hm, 2);
      const uint_t h3 = (uint_t)__shfl_down((int)hm, 3);
      if ((col & 3) == 0) {
        const ull_t pk = (ull_t)(hm & 0xffffu) | ((ull_t)(h1 & 0xffffu) << 16) |
                         ((ull_t)(h2 & 0xffffu) << 32) | ((ull_t)(h3 & 0xffffu) << 48);
        __hip_atomic_store((ull_t*)(hring + (size_t)(t + 1) * SE + so), pk,
                           __ATOMIC_RELAXED, __HIP_MEMORY_SCOPE_AGENT);
      }
      asm volatile("s_waitcnt vmcnt(0)" ::: "memory");
      __syncthreads();
      if (tid == 0)
        __hip_atomic_store(&arr[jt], (uint_t)(t + 1),
                           __ATOMIC_RELAXED, __HIP_MEMORY_SCOPE_AGENT);
      out[(size_t)t * SE + so] = hn;
      const ushort_t* xp = xwg + (((size_t)(t + 1) * 4 + btp) * 64 + jt) * 2048 + col * 32 + row;
      xq0 = xp[0]; xq1 = xp[512]; xq2 = xp[1024]; xq3 = xp[1536];
      mn = (t + 1 < T_STEPS - 1) ? (1.0f - reset[(size_t)(t + 2) * B_SZ + b]) : 1.0f;
    } else {
      out[(size_t)t * SE + so] = hn;
      float* hT = out + (size_t)T_STEPS * SE;
      float* cT = hT + SE;
      hT[so] = hn;
      cT[so] = cn;
    }
  }
}

// ---------------------------------------------------------------------------
// DIAGNOSTIC (scratch-only, deterministic): sync floor = store+drain+arrive+
// poll+broadcast, no A/GEMM/elem. 32 steps.
// ---------------------------------------------------------------------------
__global__ __launch_bounds__(512) void diag_floor(ushort_t* __restrict__ hdiag,
                                                  uint_t* __restrict__ bar2) {
  const int tid = threadIdx.x, bid = blockIdx.x;
  const int jt = bid & 63, btp = bid >> 6;
  const int lane = tid & 63, wid = tid >> 6;
  const int row = tid >> 4, col = tid & 15;
  const size_t SE = (size_t)B_SZ * H_SZ;
  const size_t so = (size_t)(btp * 32 + row) * H_SZ + jt * 16 + col;
  uint_t* const arr = bar2 + btp * 256;
  for (int t = 0; t < DIAG_STEPS; ++t) {
    if (t > 0) {
      if (wid == 0) {
        uint_t it = 0;
        for (;;) {
          const uint_t v = __hip_atomic_load(&arr[lane], __ATOMIC_RELAXED,
                                             __HIP_MEMORY_SCOPE_AGENT);
          if (__all((int)v >= t)) break;
          __builtin_amdgcn_s_sleep(1);
          if (++it > 1000000u) break;
        }
      }
      __syncthreads();
    }
    if ((col & 3) == 0)
      __hip_atomic_store((ull_t*)(hdiag + (size_t)(t + 1) * SE + so), (ull_t)t,
                         __ATOMIC_RELAXED, __HIP_MEMORY_SCOPE_AGENT);
    asm volatile("s_waitcnt vmcnt(0)" ::: "memory");
    __syncthreads();
    if (tid == 0)
      __hip_atomic_store(&arr[jt], (uint_t)(t + 1), __ATOMIC_RELAXED,
                         __HIP_MEMORY_SCOPE_AGENT);
  }
}

// ---------------------------------------------------------------------------
// DIAGNOSTIC: floor + real A-stage (cached global_load_lds of fresh tiles).
// ---------------------------------------------------------------------------
__global__ __launch_bounds__(512) void diag_nogemm(ushort_t* __restrict__ hdiag,
                                                   uint_t* __restrict__ bar2) {
  __shared__ ushort_t Ah[32 * 1024];
  const int tid = threadIdx.x, bid = blockIdx.x;
  const int jt = bid & 63, btp = bid >> 6;
  const int b0 = btp * 32;
  const int lane = tid & 63, wid = tid >> 6;
  const int row = tid >> 4, col = tid & 15;
  const size_t SE = (size_t)B_SZ * H_SZ;
  const size_t so = (size_t)(b0 + row) * H_SZ + jt * 16 + col;
  uint_t* const arr = bar2 + btp * 256;
  for (int t = 0; t < DIAG_STEPS; ++t) {
    if (t > 0) {
      if (wid == 0) {
        uint_t it = 0;
        for (;;) {
          const uint_t v = __hip_atomic_load(&arr[lane], __ATOMIC_RELAXED,
                                             __HIP_MEMORY_SCOPE_AGENT);
          if (__all((int)v >= t)) break;
          __builtin_amdgcn_s_sleep(1);
          if (++it > 1000000u) break;
        }
      }
      __syncthreads();
    }
    const char* hsrc = (const char*)(hdiag + (size_t)t * SE);
#pragma unroll
    for (int i = 0; i < 8; ++i) {
      const int c = wid * 8 + i;
      const int hrow = c >> 1;
      const int half = (c & 1) * 1024;
      const int kb = half + lane * 16;
      const int src = kb ^ ((hrow & 7) << 4);
      GLOAD_LDS16(hsrc + (size_t)(b0 + hrow) * 2048 + src,
                  (char*)Ah + hrow * 2048 + half);
    }
    __syncthreads();
    if ((col & 3) == 0)
      __hip_atomic_store((ull_t*)(hdiag + (size_t)(t + 1) * SE + so), (ull_t)t,
                         __ATOMIC_RELAXED, __HIP_MEMORY_SCOPE_AGENT);
    asm volatile("s_waitcnt vmcnt(0)" ::: "memory");
    __syncthreads();
    if (tid == 0)
      __hip_atomic_store(&arr[jt], (uint_t)(t + 1), __ATOMIC_RELAXED,
                         __HIP_MEMORY_SCOPE_AGENT);
  }
  // keep A-loads alive (rule #17): LDS content is data-dependent
  const uint_t chk = *((const uint_t*)Ah + tid);
  if (chk == 0xdeadbeefu) hdiag[0] = 1;  // scratch-only, (almost) never taken
}

extern "C" void kernel_launch(void* const* d_in, const int* in_sizes, int n_in,
                              void* d_out, int out_size, void* d_ws, size_t ws_size,
                              hipStream_t stream) {
  (void)in_sizes; (void)n_in; (void)out_size; (void)ws_size;
  const float* x = (const float*)d_in[0];
  const float* h0 = (const float*)d_in[1];
  const float* c0 = (const float*)d_in[2];
  const float* reset = (const float*)d_in[3];
  const float* W = (const float*)d_in[4];
  const float* bias = (const float*)d_in[5];
  float* out = (float*)d_out;

  const size_t TB = (size_t)T_STEPS * B_SZ;  // 16384
  const size_t SE = (size_t)B_SZ * H_SZ;     // 131072

  // ws layout (~236 MB total; proven ws_size >= 269 MB in R1)
  char* p = (char*)d_ws;
  uint_t* bar = (uint_t*)p;               p += 16384;  // [0,1k)=real, +1k/+2k words = diags
  ushort_t* WT = (ushort_t*)p;            p += (size_t)G4 * KW * 2;
  ushort_t* xbf = (ushort_t*)p;           p += TB * D_SZ * 2;
  ushort_t* xwg = (ushort_t*)p;           p += TB * G4 * 2;
  ushort_t* hbf0 = (ushort_t*)p;          p += SE * 2;
  ushort_t* hring = (ushort_t*)p;         p += (size_t)T_STEPS * SE * 2;
  ushort_t* hdiag = (ushort_t*)p;         p += (size_t)(DIAG_STEPS + 1) * SE * 2;

  hipMemsetAsync(bar, 0, 16384, stream);
  convert_x<<<dim3((int)(TB * D_SZ / 8 / 256)), 256, 0, stream>>>(x, xbf);
  transpose_w<<<dim3(KW / 32, G4 / 32), 256, 0, stream>>>(W, WT);
  init_state<<<dim3((int)((SE + 255) / 256)), 256, 0, stream>>>(h0, reset, hbf0);
  xw_mfma3<<<dim3(4096), 256, 0, stream>>>(xbf, WT, bias, xwg);

  lstm_persist7<<<dim3(256), 512, 0, stream>>>(hbf0, c0, reset, xwg, WT, out, hring, bar);

  // diagnostics (scratch-only): read their dur_us from rocprof next round
  diag_floor<<<dim3(256), 512, 0, stream>>>(hdiag, bar + 1024);
  diag_nogemm<<<dim3(256), 512, 0, stream>>>(hdiag, bar + 2048);
}

// Round 13
// 889.829 us; speedup vs baseline: 1.1130x; 1.1130x over previous
//
#include <hip/hip_runtime.h>
#include <math.h>

#define T_STEPS 128
#define B_SZ 128
#define D_SZ 1024
#define H_SZ 1024
#define G4 4096
#define KW 2048  // rows of W = D+H

typedef __attribute__((ext_vector_type(8))) short bf16x8;
typedef __attribute__((ext_vector_type(4))) float f32x4;
typedef unsigned short ushort_t;
typedef unsigned int uint_t;
typedef unsigned long long ull_t;

__device__ __forceinline__ float sigf(float x) { return 1.0f / (1.0f + __expf(-x)); }
__device__ __forceinline__ float tanhfast(float x) { return 1.0f - 2.0f * sigf(-2.0f * x); }

__device__ __forceinline__ ushort_t f2bf(float f) {
  uint_t u = __float_as_uint(f);
  return (ushort_t)((u + 0x7fffu + ((u >> 16) & 1u)) >> 16);
}
__device__ __forceinline__ float bf2f(ushort_t s) {
  return __uint_as_float(((uint_t)s) << 16);
}

#define GLOAD_LDS16(gp, lp)                                                  \
  __builtin_amdgcn_global_load_lds(                                          \
      (const __attribute__((address_space(1))) unsigned int*)(const void*)(gp), \
      (__attribute__((address_space(3))) unsigned int*)(void*)(lp), 16, 0, 0)

// ---------------------------------------------------------------------------
// x fp32 [16384][1024] -> bf16 same layout. 8 elems/thread.
// ---------------------------------------------------------------------------
__global__ __launch_bounds__(256) void convert_x(const float* __restrict__ x,
                                                 ushort_t* __restrict__ xbf) {
  const size_t i8 = ((size_t)blockIdx.x * 256 + threadIdx.x) * 8;
  if (i8 + 8 > (size_t)T_STEPS * B_SZ * D_SZ) return;
  float4 a = *(const float4*)&x[i8];
  float4 b = *(const float4*)&x[i8 + 4];
  ushort_t o[8] = {f2bf(a.x), f2bf(a.y), f2bf(a.z), f2bf(a.w),
                   f2bf(b.x), f2bf(b.y), f2bf(b.z), f2bf(b.w)};
  *(uint4*)&xbf[i8] = *(uint4*)o;
}

// ---------------------------------------------------------------------------
// W fp32 [2048][4096] -> WT bf16 [4096][2048]  (WT[n][k] = W[k][n])
// ---------------------------------------------------------------------------
__global__ __launch_bounds__(256) void transpose_w(const float* __restrict__ W,
                                                   ushort_t* __restrict__ WT) {
  __shared__ float t[32][33];
  const int tx = threadIdx.x & 31;
  const int ty = threadIdx.x >> 5;  // 0..7
  const int k0 = blockIdx.x * 32;
  const int n0 = blockIdx.y * 32;
#pragma unroll
  for (int i = 0; i < 4; ++i)
    t[ty + i * 8][tx] = W[(size_t)(k0 + ty + i * 8) * G4 + n0 + tx];
  __syncthreads();
#pragma unroll
  for (int i = 0; i < 4; ++i)
    WT[(size_t)(n0 + ty + i * 8) * KW + k0 + tx] = f2bf(t[tx][ty + i * 8]);
}

// ---------------------------------------------------------------------------
// hbf0 = bf16(h0 * (1-reset[0]))
// ---------------------------------------------------------------------------
__global__ __launch_bounds__(256) void init_state(const float* __restrict__ h0,
                                                  const float* __restrict__ reset0,
                                                  ushort_t* __restrict__ hbf0) {
  const int i = blockIdx.x * 256 + threadIdx.x;
  if (i >= B_SZ * H_SZ) return;
  hbf0[i] = f2bf(h0[i] * (1.0f - reset0[i >> 10]));
}

// ---------------------------------------------------------------------------
// Gate pre-activation from x (v3 layout, supertile-swizzled). Unchanged R11.
//   elem idx = (((t*4 + btp)*64 + jt)*2048) + g*512 + c*32 + r32
//   m = t*128 + btp*32 + r32, n = g*1024 + jt*16 + c.
// ---------------------------------------------------------------------------
__global__ __launch_bounds__(256) void xw_mfma3(const ushort_t* __restrict__ xbf,
                                                const ushort_t* __restrict__ WT,
                                                const float* __restrict__ bias,
                                                ushort_t* __restrict__ xwg) {
  __shared__ ushort_t Asb[2][128 * 64];
  __shared__ ushort_t Bsb[2][128 * 64];

  const int bid = blockIdx.x;
  const int xcd = bid & 7;
  const int ib = bid >> 3;
  const int mt = (ib >> 5) * 8 + (ib & 7);
  const int nt = xcd * 4 + ((ib >> 3) & 3);
  const int m0 = mt * 128, n0 = nt * 128;
  const int tid = threadIdx.x, lane = tid & 63, wid = tid >> 6;
  const int wr = wid >> 1, wc = wid & 1;
  const int lr = lane & 15, ko = lane >> 4;
  const int srow = lane >> 3;
  const int skb = (lane & 7) * 16;

  f32x4 acc[4][4] = {};

#define XW_STAGE(buf, kt)                                                      \
  {                                                                            \
    const int k0b = (kt) * 128;                                                \
    _Pragma("unroll") for (int i = 0; i < 4; ++i) {                            \
      const int c = wid * 4 + i;                                               \
      const int row = c * 8 + srow;                                            \
      const int sw = skb ^ ((row & 7) << 4);                                   \
      GLOAD_LDS16((const char*)xbf + (size_t)(m0 + row) * 2048 + k0b + sw,     \
                  (char*)&Asb[buf][0] + c * 1024);                             \
      GLOAD_LDS16((const char*)WT + (size_t)(n0 + row) * 4096 + k0b + sw,      \
                  (char*)&Bsb[buf][0] + c * 1024);                             \
    }                                                                          \
  }

  XW_STAGE(0, 0);
  __syncthreads();
  const int xsw = (lr & 7) << 4;
  for (int kt = 0; kt < 16; ++kt) {
    if (kt + 1 < 16) XW_STAGE((kt + 1) & 1, kt + 1);
    const char* Ab = (const char*)&Asb[kt & 1][0] + (wr * 64 + lr) * 128;
    const char* Bb = (const char*)&Bsb[kt & 1][0] + (wc * 64 + lr) * 128;
#pragma unroll
    for (int ks = 0; ks < 2; ++ks) {
      const int kb = (ks * 64 + ko * 16) ^ xsw;
      bf16x8 a[4], b[4];
#pragma unroll
      for (int mi = 0; mi < 4; ++mi) a[mi] = *(const bf16x8*)(Ab + mi * 2048 + kb);
#pragma unroll
      for (int ni = 0; ni < 4; ++ni) b[ni] = *(const bf16x8*)(Bb + ni * 2048 + kb);
#pragma unroll
      for (int mi = 0; mi < 4; ++mi)
#pragma unroll
        for (int ni = 0; ni < 4; ++ni)
          acc[mi][ni] = __builtin_amdgcn_mfma_f32_16x16x32_bf16(a[mi], b[ni], acc[mi][ni], 0, 0, 0);
    }
    __syncthreads();
  }

  const int rr = ko * 4;
#pragma unroll
  for (int ni = 0; ni < 4; ++ni) {
    const int n = n0 + wc * 64 + ni * 16 + lr;
    const int g = n >> 10;
    const int jtn = (n & 1023) >> 4;
    const float bn = bias[n];
#pragma unroll
    for (int mi = 0; mi < 4; ++mi) {
      const int m = m0 + wr * 64 + mi * 16 + rr;
      const int tt = m >> 7;
      const int btp = (m & 127) >> 5;
      const int r32 = m & 31;
      ushort_t tmp[4];
#pragma unroll
      for (int r = 0; r < 4; ++r) tmp[r] = f2bf(acc[mi][ni][r] + bn);
      *(ull_t*)(xwg + (((size_t)tt * 4 + btp) * 64 + jtn) * 2048 + g * 512 + lr * 32 + r32) =
          *(ull_t*)tmp;
    }
  }
}

// ---------------------------------------------------------------------------
// Ping-pong persistent LSTM. 256 blocks (1/CU) x 512 thr.
// Block (jt=bid&63, p=bid>>6) runs TWO independent 16-row streams:
// S0 = rows [p*16,+16) (group p), S1 = rows [(p+4)*16,+16) (group p+4).
// Streams alternate phases; each stream's poll sits ~1 half-phase after its
// peers' arrive (settle hidden under opposite GEMM), and its LDS staging is
// issued ~1 half-phase before use (flight hidden under opposite elem/drain).
// Asymmetric drains: only h-storing waves execute vmcnt(0); staging waves
// carry their load flight across the barrier.
// Wave (gw=wid&3, kh=wid>>2): gate gw, K-half kh. M=16 rows, N=16 cols,
// K=512 per wave; split-K combined in sc. Wh resident: LDS half + breg half.
// ---------------------------------------------------------------------------
__global__ __launch_bounds__(512) void lstm_pp(
    const ushort_t* __restrict__ hbf0,  // [128][1024] premasked bf16
    const float* __restrict__ c0,       // [128][1024] raw
    const float* __restrict__ reset,    // [T][128]
    const ushort_t* __restrict__ xwg,   // v3 layout, bias included
    const ushort_t* __restrict__ WT,    // [4096][2048]
    float* __restrict__ out,            // [T*128][1024] then hT, cT
    ushort_t* __restrict__ hring,       // [T][128][1024] premasked bf16 ring
    uint_t* __restrict__ bar)           // [8][256] arrival words, zeroed
{
  __shared__ ushort_t WhL[64 * 512];   // 64 KB
  __shared__ ushort_t Ah0[16 * 1024];  // 32 KB
  __shared__ ushort_t Ah1[16 * 1024];  // 32 KB
  __shared__ float sc[2][4][16][17];   // [kh][g][row][col], 8.7 KB

  const int tid = threadIdx.x;
  const int bid = blockIdx.x;
  const int jt = bid & 63;
  const int p = bid >> 6;        // 0..3
  const int b0 = p * 16;         // S0 rows
  const int b1 = (p + 4) * 16;   // S1 rows
  const int lane = tid & 63;
  const int wid = tid >> 6;
  const int gw = wid & 3;
  const int kh = wid >> 2;
  const int lr = lane & 15;
  const int ko = lane >> 4;
  const size_t SE = (size_t)B_SZ * H_SZ;

  uint_t* const arr0 = bar + p * 256;
  uint_t* const arr1 = bar + (p + 4) * 256;

  // ---- stage WhL: k in [1024,1536) (once) ----
  for (int q = 0; q < 8; ++q) {
    const int id = q * 512 + tid;
    const int wrw = id >> 6;
    const int kb = (id & 63) * 16;
    const int n = (wrw >> 4) * H_SZ + jt * 16 + (wrw & 15);
    const uint4 v = *(const uint4*)((const char*)WT + (size_t)n * 4096 + 2048 + kb);
    *(uint4*)((char*)WhL + wrw * 1024 + (kb ^ ((wrw & 7) << 4))) = v;
  }
  // ---- breg: k in [1536,2048) for wave's gate ----
  const char* wrow = (const char*)WT + (size_t)(gw * H_SZ + jt * 16 + lr) * 4096;
  bf16x8 breg[16];
#pragma unroll
  for (int q = 0; q < 16; ++q)
    breg[q] = *(const bf16x8*)(wrow + 3072 + q * 64 + ko * 16);

  // ---- per-thread elementwise identity (tid<256 -> S0, tid>=256 -> S1) ----
  const int et = tid & 255;
  const int erow = et >> 4;
  const int ecol = et & 15;
  const int eb = ((tid >> 8) ? b1 : b0) + erow;
  const int ej = jt * 16 + ecol;
  const size_t eso = (size_t)eb * H_SZ + ej;
  float creg = c0[eso] * (1.0f - reset[eb]);
  const int ebtp = eb >> 5, er32 = eb & 31;
  ushort_t xq0, xq1, xq2, xq3;
  {
    const ushort_t* xp = xwg + ((size_t)ebtp * 64 + jt) * 2048 + ecol * 32 + er32;
    xq0 = xp[0]; xq1 = xp[512]; xq2 = xp[1024]; xq3 = xp[1536];
  }
  float mn = 1.0f - reset[B_SZ + eb];

  const int swzl = (lr & 7) << 4;
  const char* a0B = (const char*)Ah0 + lr * 2048;
  const char* a1B = (const char*)Ah1 + lr * 2048;
  const char* bB = (const char*)WhL + (gw * 16 + lr) * 1024;
  const int kbase = kh * 1024;  // byte offset of this wave's K-half in row

  // ---- prologue: waves 0-3 stage Ah0 <- S0(0) from hbf0 ----
  if (wid < 4) {
#pragma unroll
    for (int i = 0; i < 8; ++i) {
      const int c = wid * 8 + i;
      const int row = c >> 1;
      const int hk = (c & 1) * 1024;
      const int kb = hk + lane * 16;
      const int src = kb ^ ((row & 7) << 4);
      GLOAD_LDS16((const char*)hbf0 + (size_t)(b0 + row) * 2048 + src,
                  (char*)Ah0 + row * 2048 + hk);
    }
  }

#define PP_GEMM(AB, ACC)                                                       \
  {                                                                            \
    _Pragma("unroll") for (int ks = 0; ks < 16; ++ks) {                        \
      const int kb = ks * 64 + ko * 16;                                        \
      bf16x8 a = *(const bf16x8*)((AB) + ((kbase + kb) ^ swzl));               \
      bf16x8 bb = kh ? breg[ks] : *(const bf16x8*)(bB + (kb ^ swzl));          \
      ACC = __builtin_amdgcn_mfma_f32_16x16x32_bf16(a, bb, ACC, 0, 0, 0);      \
    }                                                                          \
  }

#define PP_POLL(ARR, TGT)                                                      \
  {                                                                            \
    uint_t it = 0;                                                             \
    for (;;) {                                                                 \
      const uint_t v = __hip_atomic_load(&(ARR)[lane], __ATOMIC_RELAXED,       \
                                         __HIP_MEMORY_SCOPE_AGENT);            \
      if (__all((int)v >= (int)(TGT))) break;                                  \
      __builtin_amdgcn_s_sleep(1);                                             \
      if (++it > 1000000u) break;                                              \
    }                                                                          \
  }

  float* const hT = out + (size_t)T_STEPS * SE;
  float* const cT = hT + SE;

  for (int t = 0; t < T_STEPS; ++t) {
    // ================= S0 phase =================
    if (wid < 4) asm volatile("s_waitcnt vmcnt(0)" ::: "memory");  // Ah0 landed
    __syncthreads();  // #1
    f32x4 acc = {};
    PP_GEMM(a0B, acc);
    if (t > 0 && wid == 0) PP_POLL(arr1, t);  // S1(t) settle hidden under GEMM
#pragma unroll
    for (int r = 0; r < 4; ++r) sc[kh][gw][ko * 4 + r][lr] = acc[r];
    __syncthreads();  // #2: sc ready + S1-ready broadcast
    // waves 4-7: stage Ah1 <- S1(t); flight hides under elem S0 + drain
    if (wid >= 4) {
      const char* hs = (t == 0) ? (const char*)hbf0
                                : (const char*)(hring + (size_t)t * SE);
#pragma unroll
      for (int i = 0; i < 8; ++i) {
        const int c = (wid - 4) * 8 + i;
        const int row = c >> 1;
        const int hk = (c & 1) * 1024;
        const int kb = hk + lane * 16;
        const int src = kb ^ ((row & 7) << 4);
        GLOAD_LDS16(hs + (size_t)(b1 + row) * 2048 + src,
                    (char*)Ah1 + row * 2048 + hk);
      }
    }
    float hn0 = 0.0f;
    if (tid < 256) {  // elem S0
      const float gi = sc[0][0][erow][ecol] + sc[1][0][erow][ecol] + bf2f(xq0);
      const float gg = sc[0][1][erow][ecol] + sc[1][1][erow][ecol] + bf2f(xq1);
      const float gf = sc[0][2][erow][ecol] + sc[1][2][erow][ecol] + bf2f(xq2);
      const float go = sc[0][3][erow][ecol] + sc[1][3][erow][ecol] + bf2f(xq3);
      const float f = sigf(gf + 1.0f);
      const float cn = f * creg + sigf(gi) * tanhfast(gg);
      const float hn = sigf(go) * tanhfast(cn);
      creg = cn * mn;
      hn0 = hn;
      if (t < T_STEPS - 1) {
        const uint_t hm = (uint_t)f2bf(hn * mn);
        const uint_t h1 = (uint_t)__shfl_down((int)hm, 1);
        const uint_t h2 = (uint_t)__shfl_down((int)hm, 2);
        const uint_t h3 = (uint_t)__shfl_down((int)hm, 3);
        if ((ecol & 3) == 0) {
          const ull_t pk = (ull_t)(hm & 0xffffu) | ((ull_t)(h1 & 0xffffu) << 16) |
                           ((ull_t)(h2 & 0xffffu) << 32) | ((ull_t)(h3 & 0xffffu) << 48);
          __hip_atomic_store((ull_t*)(hring + (size_t)(t + 1) * SE + eso), pk,
                             __ATOMIC_RELAXED, __HIP_MEMORY_SCOPE_AGENT);
        }
      } else {
        hT[eso] = hn;
        cT[eso] = cn;
      }
      asm volatile("s_waitcnt vmcnt(0)" ::: "memory");  // drain h0 only
    }
    __syncthreads();  // #3: h0 drained block-wide
    if (tid == 0 && t < T_STEPS - 1)
      __hip_atomic_store(&arr0[jt], (uint_t)(t + 1), __ATOMIC_RELAXED,
                         __HIP_MEMORY_SCOPE_AGENT);
    if (tid < 256) {
      out[(size_t)t * SE + eso] = hn0;
      if (t < T_STEPS - 1) {
        const ushort_t* xp =
            xwg + (((size_t)(t + 1) * 4 + ebtp) * 64 + jt) * 2048 + ecol * 32 + er32;
        xq0 = xp[0]; xq1 = xp[512]; xq2 = xp[1024]; xq3 = xp[1536];
        mn = (t + 1 < T_STEPS - 1) ? (1.0f - reset[(size_t)(t + 2) * B_SZ + eb]) : 1.0f;
      }
    }
    if (wid >= 4) asm volatile("s_waitcnt vmcnt(0)" ::: "memory");  // Ah1 landed
    __syncthreads();  // #4

    // ================= S1 phase =================
    f32x4 acc2 = {};
    PP_GEMM(a1B, acc2);
    if (t < T_STEPS - 1 && wid == 0) PP_POLL(arr0, t + 1);  // S0(t+1) settle
#pragma unroll
    for (int r = 0; r < 4; ++r) sc[kh][gw][ko * 4 + r][lr] = acc2[r];
    __syncthreads();  // #5: sc ready + S0(t+1)-ready broadcast
    // waves 0-3: stage Ah0 <- S0(t+1); flight hides under elem S1 + drain
    if (wid < 4 && t < T_STEPS - 1) {
      const char* hs = (const char*)(hring + (size_t)(t + 1) * SE);
#pragma unroll
      for (int i = 0; i < 8; ++i) {
        const int c = wid * 8 + i;
        const int row = c >> 1;
        const int hk = (c & 1) * 1024;
        const int kb = hk + lane * 16;
        const int src = kb ^ ((row & 7) << 4);
        GLOAD_LDS16(hs + (size_t)(b0 + row) * 2048 + src,
                    (char*)Ah0 + row * 2048 + hk);
      }
    }
    float hn1 = 0.0f;
    if (tid >= 256) {  // elem S1
      const float gi = sc[0][0][erow][ecol] + sc[1][0][erow][ecol] + bf2f(xq0);
      const float gg = sc[0][1][erow][ecol] + sc[1][1][erow][ecol] + bf2f(xq1);
      const float gf = sc[0][2][erow][ecol] + sc[1][2][erow][ecol] + bf2f(xq2);
      const float go = sc[0][3][erow][ecol] + sc[1][3][erow][ecol] + bf2f(xq3);
      const float f = sigf(gf + 1.0f);
      const float cn = f * creg + sigf(gi) * tanhfast(gg);
      const float hn = sigf(go) * tanhfast(cn);
      creg = cn * mn;
      hn1 = hn;
      if (t < T_STEPS - 1) {
        const uint_t hm = (uint_t)f2bf(hn * mn);
        const uint_t h1 = (uint_t)__shfl_down((int)hm, 1);
        const uint_t h2 = (uint_t)__shfl_down((int)hm, 2);
        const uint_t h3 = (uint_t)__shfl_down((int)hm, 3);
        if ((ecol & 3) == 0) {
          const ull_t pk = (ull_t)(hm & 0xffffu) | ((ull_t)(h1 & 0xffffu) << 16) |
                           ((ull_t)(h2 & 0xffffu) << 32) | ((ull_t)(h3 & 0xffffu) << 48);
          __hip_atomic_store((ull_t*)(hring + (size_t)(t + 1) * SE + eso), pk,
                             __ATOMIC_RELAXED, __HIP_MEMORY_SCOPE_AGENT);
        }
      } else {
        hT[eso] = hn;
        cT[eso] = cn;
      }
      asm volatile("s_waitcnt vmcnt(0)" ::: "memory");  // drain h1 only
    }
    __syncthreads();  // #6: h1 drained block-wide
    if (tid == 256 && t < T_STEPS - 1)
      __hip_atomic_store(&arr1[jt], (uint_t)(t + 1), __ATOMIC_RELAXED,
                         __HIP_MEMORY_SCOPE_AGENT);
    if (tid >= 256) {
      out[(size_t)t * SE + eso] = hn1;
      if (t < T_STEPS - 1) {
        const ushort_t* xp =
            xwg + (((size_t)(t + 1) * 4 + ebtp) * 64 + jt) * 2048 + ecol * 32 + er32;
        xq0 = xp[0]; xq1 = xp[512]; xq2 = xp[1024]; xq3 = xp[1536];
        mn = (t + 1 < T_STEPS - 1) ? (1.0f - reset[(size_t)(t + 2) * B_SZ + eb]) : 1.0f;
      }
    }
  }
}

extern "C" void kernel_launch(void* const* d_in, const int* in_sizes, int n_in,
                              void* d_out, int out_size, void* d_ws, size_t ws_size,
                              hipStream_t stream) {
  (void)in_sizes; (void)n_in; (void)out_size; (void)ws_size;
  const float* x = (const float*)d_in[0];
  const float* h0 = (const float*)d_in[1];
  const float* c0 = (const float*)d_in[2];
  const float* reset = (const float*)d_in[3];
  const float* W = (const float*)d_in[4];
  const float* bias = (const float*)d_in[5];
  float* out = (float*)d_out;

  const size_t TB = (size_t)T_STEPS * B_SZ;  // 16384
  const size_t SE = (size_t)B_SZ * H_SZ;     // 131072

  // ws layout (~218 MB; proven ws_size >= 269 MB in R1)
  char* p = (char*)d_ws;
  uint_t* bar = (uint_t*)p;               p += 16384;
  ushort_t* WT = (ushort_t*)p;            p += (size_t)G4 * KW * 2;
  ushort_t* xbf = (ushort_t*)p;           p += TB * D_SZ * 2;
  ushort_t* xwg = (ushort_t*)p;           p += TB * G4 * 2;
  ushort_t* hbf0 = (ushort_t*)p;          p += SE * 2;
  ushort_t* hring = (ushort_t*)p;         p += (size_t)T_STEPS * SE * 2;

  hipMemsetAsync(bar, 0, 16384, stream);
  convert_x<<<dim3((int)(TB * D_SZ / 8 / 256)), 256, 0, stream>>>(x, xbf);
  transpose_w<<<dim3(KW / 32, G4 / 32), 256, 0, stream>>>(W, WT);
  init_state<<<dim3((int)((SE + 255) / 256)), 256, 0, stream>>>(h0, reset, hbf0);
  xw_mfma3<<<dim3(4096), 256, 0, stream>>>(xbf, WT, bias, xwg);

  lstm_pp<<<dim3(256), 512, 0, stream>>>(hbf0, c0, reset, xwg, WT, out, hring, bar);
}